// Round 14
// baseline (4482.574 us; speedup 1.0000x reference)
//
#include <hip/hip_runtime.h>

typedef _Float16 f16x8 __attribute__((ext_vector_type(8)));
typedef float f32x4 __attribute__((ext_vector_type(4)));

// Packed ("fragment-major") A layout: half-index of element (row,k), row-length K:
//   off = (row>>4)*(K*16) + (k>>5)*512 + ((((k>>3)&3)*16 + (row&15))*8) + (k&7)
// A wave reading lane*8..lane*8+7 at one kstep gets a contiguous 1KB block ==
// its MFMA A-fragment (row = lane&15, k = kstep*32 + (lane>>4)*8 + e).
//
// stats layout (floats):
//  [0..31] x sum   [32..63] x sumsq   [64..95] y sum   [96..127] y sumsq
//  [128] finalize counter (int)
//  [129..192] x mwg counters (64 ints)   [193..320] y mwg counters (128 ints)
//  [324..355] scx  [356..387] shx  [388..419] scy  [420..451] shy

__device__ inline unsigned short f16b(float v) {
    _Float16 h = (_Float16)v;
    return __builtin_bit_cast(unsigned short, h);
}

__device__ inline void atomAddF(float* p, float v) {
    __hip_atomic_fetch_add(p, v, __ATOMIC_RELAXED, __HIP_MEMORY_SCOPE_AGENT);
}

template<int K>
__device__ inline void pack_cvt(const float* __restrict__ src, unsigned short* __restrict__ dst, int u) {
    int o = u * 8;
    int panel = o / (K * 16);
    int rem = o - panel * (K * 16);
    int kstep = rem >> 9;
    int rem2 = rem & 511;
    int g = rem2 >> 7;
    int r15 = (rem2 >> 3) & 15;
    int row = (panel << 4) | r15;
    int k = (kstep << 5) | (g << 3);
    const float4* s = (const float4*)(src + (size_t)row * K + k);
    float4 v0 = s[0], v1 = s[1];
    uint4 q;
    q.x = (unsigned)f16b(v0.x) | ((unsigned)f16b(v0.y) << 16);
    q.y = (unsigned)f16b(v0.z) | ((unsigned)f16b(v0.w) << 16);
    q.z = (unsigned)f16b(v1.x) | ((unsigned)f16b(v1.y) << 16);
    q.w = (unsigned)f16b(v1.z) | ((unsigned)f16b(v1.w) << 16);
    ((uint4*)dst)[u] = q;
}

// ---------------- prep: blocks [0,2048) cvt W/WL; [2048,6144) transpose P ----------------
__global__ __launch_bounds__(256) void prep(const float* __restrict__ W, const float* __restrict__ WL,
                                            const float* __restrict__ P,
                                            unsigned short* __restrict__ Wb, unsigned short* __restrict__ WLb,
                                            unsigned short* __restrict__ Pb, unsigned short* __restrict__ PT) {
    __shared__ unsigned int lds[64][33];
    int bid = blockIdx.x;
    if (bid < 2048) {
        const int NW = 1572864, TOT = 1572864 + 6291456;
        for (int u = bid * 256 + threadIdx.x; u < TOT; u += 2048 * 256) {
            if (u < NW) pack_cvt<6144>(W, Wb, u);
            else pack_cvt<12288>(WL, WLb, u - NW);
        }
        return;
    }
    int vb = bid - 2048;
    int m0 = (vb & 127) * 32;
    int n0 = (vb >> 7) * 64;
    int tid = threadIdx.x;
    const float2* P2 = (const float2*)P;
    #pragma unroll
    for (int it = 0; it < 8; ++it) {
        int idx = it * 256 + tid;
        int nl = idx >> 5, ml = idx & 31;
        float2 v = P2[(size_t)(n0 + nl) * 4096 + (m0 + ml)];
        unsigned int pk = (unsigned int)f16b(v.x) | ((unsigned int)f16b(v.y) << 16);
        lds[nl][ml] = pk;
    }
    __syncthreads();
    unsigned int* PTu = (unsigned int*)PT;
    #pragma unroll
    for (int it = 0; it < 8; ++it) {
        int idx = it * 256 + tid;
        int ml = idx >> 6, nl = idx & 63;
        int row = m0 + ml;
        int k2 = (n0 + nl) * 2;
        int o = ((row >> 4) << 16) | ((k2 >> 5) << 9) | (((((k2 >> 3) & 3) << 4) | (row & 15)) << 3) | (k2 & 7);
        PTu[o >> 1] = lds[nl][ml];
    }
    unsigned int* Pbu = (unsigned int*)Pb;
    #pragma unroll
    for (int it = 0; it < 8; ++it) {
        int idx = it * 256 + tid;
        int nl = idx >> 5, ml = idx & 31;
        int row = n0 + nl;
        int k = (m0 + ml) * 2;
        int o = (row >> 4) * 131072 + ((k >> 5) << 9) + (((((k >> 3) & 3) << 4) | (row & 15)) << 3) + (k & 7);
        Pbu[o >> 1] = lds[nl][ml];
    }
}

// ---------------- B-matrix build + stats/counter zeroing ----------------
__global__ __launch_bounds__(256) void build_b(
    const float* __restrict__ srcx, const float* __restrict__ srcy,
    int Fin, int Fout, int buildB2, int use_bn,
    float* __restrict__ stats,
    const float* __restrict__ w1a, const float* __restrict__ w1b,
    const float* __restrict__ w2a, const float* __restrict__ w2b,
    unsigned short* __restrict__ B1f, unsigned short* __restrict__ B2f) {
    if (blockIdx.x == 0) {
        // zero sums + finalize counter + mwg counters ([0..320]); sc/sh preserved
        stats[threadIdx.x] = 0.f;
        if (threadIdx.x < 65) stats[256 + threadIdx.x] = 0.f;
    }
    int tid0 = blockIdx.x * 256 + threadIdx.x;
    const int NB1 = 14336 * 32;
    int isB2 = 0, t2 = tid0;
    if (tid0 >= NB1) {
        if (!buildB2) return;
        isB2 = 1; t2 = tid0 - NB1;
        if (t2 >= 16384 * 32) return;
    }
    int e = t2 & 7, lane = (t2 >> 3) & 63, hh = (t2 >> 9) & 1, t = t2 >> 10;
    int k = (t << 5) | ((lane >> 4) << 3) | e;
    int g = (hh << 4) | (lane & 15);
    float v = 0.f;
    if (g < Fout) {
        const float* hr; const float* wc; int useY;
        if (!isB2) {
            if (k < 6144) { int m = k / 3, j = k - 3 * m; hr = srcx + m * Fin; wc = w1a + (j * Fin) * Fout + g; useY = 0; }
            else { int k2 = k - 6144; int m = k2 >> 1, p = k2 & 1; hr = srcy + m * Fin; wc = w1b + (p * Fin) * Fout + g; useY = 1; }
        } else {
            if (k < 12288) { int m = k / 3, j = k - 3 * m; hr = srcy + m * Fin; wc = w2a + (j * Fin) * Fout + g; useY = 1; }
            else { int k2 = k - 12288; int n = k2 >> 1, p = k2 & 1; hr = srcx + n * Fin; wc = w2b + (p * Fin) * Fout + g; useY = 0; }
        }
        float a = 0.f;
        if (use_bn) {
            const float* sc = useY ? stats + 388 : stats + 324;
            const float* sh = useY ? stats + 420 : stats + 356;
            #pragma unroll
            for (int f = 0; f < 32; ++f) {
                float h = sc[f] * hr[f] + sh[f];
                a += h * wc[f * Fout];
            }
        } else {
            for (int f = 0; f < Fin; ++f) a += hr[f] * wc[f * Fout];
        }
        v = a;
    }
    if (!isB2) B1f[t2] = f16b(v); else B2f[t2] = f16b(v);
}

// ---------------- GEMM + fused reduce/stats/BN (or final output) epilogue ----------------
// x-branch: 64 mwgs x 14 ksegs = 896 WGs; y-branch: 128 mwgs x 16 ksegs = 2048 WGs
template<int FINAL>
__global__ __launch_bounds__(256) void gemm_k(
    const unsigned short* __restrict__ Wb, const unsigned short* __restrict__ Pb,
    const unsigned short* __restrict__ WLb, const unsigned short* __restrict__ PTb,
    const unsigned short* __restrict__ B1f, const unsigned short* __restrict__ B2f,
    float* __restrict__ px, float* __restrict__ py,
    const float* __restrict__ bx, const float* __restrict__ by,
    const float* __restrict__ gx, const float* __restrict__ btx,
    const float* __restrict__ gy, const float* __restrict__ bty,
    float* __restrict__ zax, float* __restrict__ zay,
    float* __restrict__ stats,
    const float* __restrict__ bl, float* __restrict__ out,
    int nwgx) {
    __shared__ __align__(16) float lds[4][1024];
    __shared__ int lastFlag;
    int bid = blockIdx.x;
    const unsigned short* Bf;
    float* Z;
    int seg, Mbase, K, kloc, kb, isX, mwg, nsegs;
    const unsigned short* A16;
    if (bid < nwgx) {
        Bf = B1f; isX = 1;
        mwg = bid / 14; seg = bid % 14; nsegs = 14;
        Mbase = mwg * 32;
        kb = seg << 10;
        Z = px + (size_t)seg * 65536;
        if (seg < 6) { K = 6144; kloc = kb;        A16 = Wb; }
        else         { K = 8192; kloc = kb - 6144; A16 = Pb; }
    } else {
        int b2 = bid - nwgx;
        Bf = B2f; isX = 0;
        mwg = b2 / 16; seg = b2 % 16; nsegs = 16;
        Mbase = mwg * 32;
        kb = seg << 10;
        Z = py + (size_t)seg * 131072;
        if (seg < 12) { K = 12288; kloc = kb;         A16 = WLb; }
        else          { K = 4096;  kloc = kb - 12288; A16 = PTb; }
    }
    int wid = threadIdx.x >> 6, lane = threadIdx.x & 63;
    int kq = wid << 8;
    const unsigned short* ap0 = A16 + (size_t)(Mbase >> 4) * (K * 16)
                              + (size_t)((kloc + kq) >> 5) * 512 + lane * 8;
    const unsigned short* ap1 = ap0 + (size_t)K * 16;
    const unsigned short* bp = Bf + ((size_t)((kb + kq) >> 5)) * 1024 + lane * 8;
    f32x4 acc00 = {0.f,0.f,0.f,0.f}, acc01 = {0.f,0.f,0.f,0.f};
    f32x4 acc10 = {0.f,0.f,0.f,0.f}, acc11 = {0.f,0.f,0.f,0.f};
    #pragma unroll
    for (int ks = 0; ks < 8; ++ks) {
        f16x8 a0 = *(const f16x8*)ap0;
        f16x8 a1 = *(const f16x8*)ap1;
        f16x8 b0 = *(const f16x8*)bp;
        f16x8 b1 = *(const f16x8*)(bp + 512);
        acc00 = __builtin_amdgcn_mfma_f32_16x16x32_f16(a0, b0, acc00, 0, 0, 0);
        acc10 = __builtin_amdgcn_mfma_f32_16x16x32_f16(a1, b0, acc10, 0, 0, 0);
        acc01 = __builtin_amdgcn_mfma_f32_16x16x32_f16(a0, b1, acc01, 0, 0, 0);
        acc11 = __builtin_amdgcn_mfma_f32_16x16x32_f16(a1, b1, acc11, 0, 0, 0);
        ap0 += 512; ap1 += 512; bp += 1024;
    }
    int col = lane & 15, r0 = (lane >> 4) << 2;
    float* l = lds[wid];
    #pragma unroll
    for (int r = 0; r < 4; ++r) {
        l[(r0 + r) * 32 + col]            = acc00[r];
        l[(r0 + r) * 32 + col + 16]       = acc01[r];
        l[(r0 + r + 16) * 32 + col]       = acc10[r];
        l[(r0 + r + 16) * 32 + col + 16]  = acc11[r];
    }
    __syncthreads();
    int tid = threadIdx.x;
    {
        float4 a = ((const float4*)lds[0])[tid];
        float4 b = ((const float4*)lds[1])[tid];
        float4 c = ((const float4*)lds[2])[tid];
        float4 d = ((const float4*)lds[3])[tid];
        float4 s;
        s.x = (a.x + b.x) + (c.x + d.x);
        s.y = (a.y + b.y) + (c.y + d.y);
        s.z = (a.z + b.z) + (c.z + d.z);
        s.w = (a.w + b.w) + (c.w + d.w);
        ((float4*)(Z + (size_t)Mbase * 32))[tid] = s;
    }
    // ---- epilogue: last WG per row-group reduces its 32 rows ----
    __threadfence();
    if (tid == 0) {
        int* cnt = (int*)stats + (isX ? (129 + mwg) : (193 + mwg));
        int old = __hip_atomic_fetch_add(cnt, 1, __ATOMIC_ACQ_REL, __HIP_MEMORY_SCOPE_AGENT);
        lastFlag = (old == nsegs - 1) ? 1 : 0;
    }
    __syncthreads();
    if (!lastFlag) return;
    __threadfence();
    if (FINAL) {
        if (tid < 64) {
            int n = Mbase + (tid >> 1), c = tid & 1;
            float a = bl[c];
            for (int s = 0; s < 14; ++s) a += px[(size_t)s * 65536 + n * 32 + c];
            out[n * 2 + c] = a;
        }
        return;
    }
    __syncthreads();  // lds reuse below
    float (*lsum)[8][8] = (float (*)[8][8])lds;
    const float4* src4; const float* bias; float4* dst; float* st; int stride4;
    if (isX) { src4 = (const float4*)px; bias = bx; dst = (float4*)zax; st = stats;      stride4 = 16384; }
    else     { src4 = (const float4*)py; bias = by; dst = (float4*)zay; st = stats + 64; stride4 = 32768; }
    int i4 = mwg * 256 + tid;
    float4 s = {0.f, 0.f, 0.f, 0.f};
    for (int gI = 0; gI < nsegs; ++gI) {
        float4 v = src4[(size_t)gI * stride4 + i4];
        s.x += v.x; s.y += v.y; s.z += v.z; s.w += v.w;
    }
    int c0 = (i4 & 7) * 4;
    float4 b4 = *(const float4*)(bias + c0);
    s.x += b4.x; s.y += b4.y; s.z += b4.z; s.w += b4.w;
    if (c0 < 16) {
        s.x = fmaxf(s.x, 0.f); s.y = fmaxf(s.y, 0.f);
        s.z = fmaxf(s.z, 0.f); s.w = fmaxf(s.w, 0.f);
    }
    dst[i4] = s;
    float4 s2 = {s.x * s.x, s.y * s.y, s.z * s.z, s.w * s.w};
    #pragma unroll
    for (int mask = 8; mask <= 32; mask <<= 1) {
        s.x += __shfl_xor(s.x, mask); s.y += __shfl_xor(s.y, mask);
        s.z += __shfl_xor(s.z, mask); s.w += __shfl_xor(s.w, mask);
        s2.x += __shfl_xor(s2.x, mask); s2.y += __shfl_xor(s2.y, mask);
        s2.z += __shfl_xor(s2.z, mask); s2.w += __shfl_xor(s2.w, mask);
    }
    int w = tid >> 6, ln = tid & 63;
    if (ln < 8) {
        lsum[w][ln][0] = s.x;  lsum[w][ln][1] = s.y;  lsum[w][ln][2] = s.z;  lsum[w][ln][3] = s.w;
        lsum[w][ln][4] = s2.x; lsum[w][ln][5] = s2.y; lsum[w][ln][6] = s2.z; lsum[w][ln][7] = s2.w;
    }
    __syncthreads();
    if (tid < 64) {
        int q = tid >> 3, e = tid & 7;
        float v = lsum[0][q][e] + lsum[1][q][e] + lsum[2][q][e] + lsum[3][q][e];
        int colI = q * 4 + (e & 3);
        atomAddF((e < 4) ? &st[colI] : &st[32 + colI], v);
    }
    __syncthreads();
    if (tid == 0) {
        __threadfence();
        int old = __hip_atomic_fetch_add((int*)stats + 128, 1, __ATOMIC_ACQ_REL, __HIP_MEMORY_SCOPE_AGENT);
        lastFlag = (old == 191) ? 1 : 0;
    }
    __syncthreads();
    if (lastFlag && tid < 64) {
        __threadfence();
        int f = tid & 31, isY = tid >> 5;
        float* sb = stats + (isY ? 64 : 0);
        float n = isY ? 4096.f : 2048.f;
        float sum = __hip_atomic_load(&sb[f], __ATOMIC_RELAXED, __HIP_MEMORY_SCOPE_AGENT);
        float ssq = __hip_atomic_load(&sb[32 + f], __ATOMIC_RELAXED, __HIP_MEMORY_SCOPE_AGENT);
        float mean = sum / n;
        float var = ssq / n - mean * mean;
        const float* gv = isY ? gy : gx;
        const float* bv = isY ? bty : btx;
        float sc = gv[f] * rsqrtf(var + 1e-5f);
        stats[324 + isY * 64 + f] = sc;
        stats[356 + isY * 64 + f] = bv[f] - mean * sc;
    }
}

extern "C" void kernel_launch(void* const* d_in, const int* in_sizes, int n_in,
                              void* d_out, int out_size, void* d_ws, size_t ws_size,
                              hipStream_t stream) {
    const float* W    = (const float*)d_in[0];
    const float* x    = (const float*)d_in[1];
    const float* WL   = (const float*)d_in[2];
    const float* y    = (const float*)d_in[3];
    const float* P    = (const float*)d_in[4];
    const float* wx2x0 = (const float*)d_in[5];
    const float* wy2x0 = (const float*)d_in[6];
    const float* bx0   = (const float*)d_in[7];
    const float* wy2y0 = (const float*)d_in[8];
    const float* wx2y0 = (const float*)d_in[9];
    const float* by0   = (const float*)d_in[10];
    const float* gx0   = (const float*)d_in[11];
    const float* btx0  = (const float*)d_in[12];
    const float* gy0   = (const float*)d_in[13];
    const float* bty0  = (const float*)d_in[14];
    const float* wx2x_m = (const float*)d_in[15];
    const float* wy2x_m = (const float*)d_in[16];
    const float* bx_m   = (const float*)d_in[17];
    const float* wy2y_m = (const float*)d_in[18];
    const float* wx2y_m = (const float*)d_in[19];
    const float* by_m   = (const float*)d_in[20];
    const float* gx_m   = (const float*)d_in[21];
    const float* btx_m  = (const float*)d_in[22];
    const float* gy_m   = (const float*)d_in[23];
    const float* bty_m  = (const float*)d_in[24];
    const float* wlx = (const float*)d_in[25];
    const float* wly = (const float*)d_in[26];
    const float* bl  = (const float*)d_in[27];

    char* base = (char*)d_ws;
    unsigned short* Wb  = (unsigned short*)(base + 0);          // 25,165,824 B
    unsigned short* Pb  = (unsigned short*)(base + 25165824);   // 33,554,432 B
    unsigned short* WLb = (unsigned short*)(base + 58720256);   // 100,663,296 B
    unsigned short* PTb = (unsigned short*)(base + 159383552);  // 33,554,432 B
    unsigned short* B1f = (unsigned short*)(base + 192937984);  // 917,504 B
    unsigned short* B2f = (unsigned short*)(base + 193855488);  // 1,048,576 B
    float* zax   = (float*)(base + 194904064);  // 262,144 B
    float* zay   = (float*)(base + 195166208);  // 524,288 B
    float* stats = (float*)(base + 195690496);  // 2,048 B
    float* px    = (float*)(base + 195692544);  // 3,670,016 B
    float* py    = (float*)(base + 199362560);  // 8,388,608 B
    float* outp  = (float*)d_out;

    prep<<<6144, 256, 0, stream>>>(W, WL, P, Wb, WLb, Pb, PTb);

    // layer 0 (Fin = 1, raw x/y, no bn)
    build_b<<<3840, 256, 0, stream>>>(x, y, 1, 32, 1, 0, stats,
                                      wx2x0, wy2x0, wy2y0, wx2y0, B1f, B2f);
    gemm_k<0><<<2944, 256, 0, stream>>>(Wb, Pb, WLb, PTb, B1f, B2f, px, py,
                                        bx0, by0, gx0, btx0, gy0, bty0,
                                        zax, zay, stats, nullptr, nullptr, 896);

    // middle blocks 1..6
    for (int i = 0; i < 6; ++i) {
        build_b<<<3840, 256, 0, stream>>>(zax, zay, 32, 32, 1, 1, stats,
                                          wx2x_m + i * 3072, wy2x_m + i * 2048,
                                          wy2y_m + i * 3072, wx2y_m + i * 2048, B1f, B2f);
        gemm_k<0><<<2944, 256, 0, stream>>>(Wb, Pb, WLb, PTb, B1f, B2f, px, py,
                                            bx_m + i * 32, by_m + i * 32,
                                            gx_m + i * 32, btx_m + i * 32,
                                            gy_m + i * 32, bty_m + i * 32,
                                            zax, zay, stats, nullptr, nullptr, 896);
    }

    // final layer: x-branch only, writes out in epilogue
    build_b<<<1792, 256, 0, stream>>>(zax, zay, 32, 2, 0, 1, stats,
                                      wlx, wly, nullptr, nullptr, B1f, B2f);
    gemm_k<1><<<896, 256, 0, stream>>>(Wb, Pb, WLb, PTb, B1f, B2f, px, py,
                                       nullptr, nullptr, nullptr, nullptr, nullptr, nullptr,
                                       zax, zay, stats, bl, outp, 896);
}

// Round 15
// 618.324 us; speedup vs baseline: 7.2496x; 7.2496x over previous
//
#include <hip/hip_runtime.h>

typedef _Float16 f16x8 __attribute__((ext_vector_type(8)));
typedef float f32x4 __attribute__((ext_vector_type(4)));

// Packed ("fragment-major") A layout: half-index of element (row,k), row-length K:
//   off = (row>>4)*(K*16) + (k>>5)*512 + ((((k>>3)&3)*16 + (row&15))*8) + (k&7)
// A wave reading lane*8..lane*8+7 at one kstep gets a contiguous 1KB block ==
// its MFMA A-fragment (row = lane&15, k = kstep*32 + (lane>>4)*8 + e).
//
// stats layout (floats): [0..63] x sums (sum,sumsq), [64..127] y sums, [128] counter,
//                        [132..163] scx, [164..195] shx, [196..227] scy, [228..259] shy

__device__ inline unsigned short f16b(float v) {
    _Float16 h = (_Float16)v;
    return __builtin_bit_cast(unsigned short, h);
}

__device__ inline void atomAddF(float* p, float v) {
    __hip_atomic_fetch_add(p, v, __ATOMIC_RELAXED, __HIP_MEMORY_SCOPE_AGENT);
}

// ---------------- fp32 -> packed fp16, 4 units (one 128B src row-chunk) per call ----------------
// quad q -> blk = q>>4 (panel,kstep), r15 = q&15; reads row (panel*16+r15),
// k = kstep*32 .. +32 (128B contiguous); writes units blk*64 + g*16 + r15, g=0..3.
template<int K>
__device__ inline void pack_cvt4(const float* __restrict__ src, unsigned short* __restrict__ dst, int q) {
    const int KSTEPS = K / 32;
    int r15 = q & 15;
    int blk = q >> 4;
    int panel = blk / KSTEPS;
    int kstep = blk - panel * KSTEPS;
    int row = (panel << 4) | r15;
    const float4* s = (const float4*)(src + (size_t)row * K + (kstep << 5));
    uint4* d = (uint4*)dst;
    #pragma unroll
    for (int g = 0; g < 4; ++g) {
        float4 v0 = s[g * 2], v1 = s[g * 2 + 1];
        uint4 qq;
        qq.x = (unsigned)f16b(v0.x) | ((unsigned)f16b(v0.y) << 16);
        qq.y = (unsigned)f16b(v0.z) | ((unsigned)f16b(v0.w) << 16);
        qq.z = (unsigned)f16b(v1.x) | ((unsigned)f16b(v1.y) << 16);
        qq.w = (unsigned)f16b(v1.z) | ((unsigned)f16b(v1.w) << 16);
        d[(size_t)blk * 64 + g * 16 + r15] = qq;
    }
}

// ---------------- prep: blocks [0,2048) cvt W/WL; [2048,6144) transpose P ----------------
__global__ __launch_bounds__(256) void prep(const float* __restrict__ W, const float* __restrict__ WL,
                                            const float* __restrict__ P,
                                            unsigned short* __restrict__ Wb, unsigned short* __restrict__ WLb,
                                            unsigned short* __restrict__ Pb, unsigned short* __restrict__ PT) {
    __shared__ unsigned int lds[64][33];
    int bid = blockIdx.x;
    if (bid < 2048) {
        const int QW = 393216, QTOT = 393216 + 1572864;
        for (int q = bid * 256 + threadIdx.x; q < QTOT; q += 2048 * 256) {
            if (q < QW) pack_cvt4<6144>(W, Wb, q);
            else pack_cvt4<12288>(WL, WLb, q - QW);
        }
        return;
    }
    int vb = bid - 2048;
    int m0 = (vb & 127) * 32;
    int n0 = (vb >> 7) * 64;
    int tid = threadIdx.x;
    const float2* P2 = (const float2*)P;
    #pragma unroll
    for (int it = 0; it < 8; ++it) {
        int idx = it * 256 + tid;
        int nl = idx >> 5, ml = idx & 31;
        float2 v = P2[(size_t)(n0 + nl) * 4096 + (m0 + ml)];
        unsigned int pk = (unsigned int)f16b(v.x) | ((unsigned int)f16b(v.y) << 16);
        lds[nl][ml] = pk;
    }
    __syncthreads();
    // y-branch PT: row = m, k = n*2+p  (K=4096)
    unsigned int* PTu = (unsigned int*)PT;
    #pragma unroll
    for (int it = 0; it < 8; ++it) {
        int idx = it * 256 + tid;
        int ml = idx >> 6, nl = idx & 63;
        int row = m0 + ml;
        int k2 = (n0 + nl) * 2;
        int o = ((row >> 4) << 16) | ((k2 >> 5) << 9) | (((((k2 >> 3) & 3) << 4) | (row & 15)) << 3) | (k2 & 7);
        PTu[o >> 1] = lds[nl][ml];
    }
    // x-branch Pb: row = n, k = m*2+p  (K=8192)
    unsigned int* Pbu = (unsigned int*)Pb;
    #pragma unroll
    for (int it = 0; it < 8; ++it) {
        int idx = it * 256 + tid;
        int nl = idx >> 5, ml = idx & 31;
        int row = n0 + nl;
        int k = (m0 + ml) * 2;
        int o = (row >> 4) * 131072 + ((k >> 5) << 9) + (((((k >> 3) & 3) << 4) | (row & 15)) << 3) + (k & 7);
        Pbu[o >> 1] = lds[nl][ml];
    }
}

// ---------------- B-matrix build: thread = (k-row, g); hr broadcast, wc coalesced ----------------
__global__ __launch_bounds__(256) void build_b(
    const float* __restrict__ srcx, const float* __restrict__ srcy,
    int Fin, int Fout, int buildB2, int use_bn,
    const float* __restrict__ stats,
    const float* __restrict__ w1a, const float* __restrict__ w1b,
    const float* __restrict__ w2a, const float* __restrict__ w2b,
    unsigned short* __restrict__ B1f, unsigned short* __restrict__ B2f) {
    int t2 = blockIdx.x * 256 + threadIdx.x;
    const int NB1 = 14336 * 32;
    int isB2 = 0;
    if (t2 >= NB1) {
        if (!buildB2) return;
        isB2 = 1; t2 -= NB1;
        if (t2 >= 16384 * 32) return;
    }
    int g = t2 & 31;
    int k = t2 >> 5;
    float v = 0.f;
    if (g < Fout) {
        const float* hr; const float* wc; int useY;
        if (!isB2) {
            if (k < 6144) { int m = k / 3, j = k - 3 * m; hr = srcx + m * Fin; wc = w1a + (j * Fin) * Fout + g; useY = 0; }
            else { int k2 = k - 6144; int m = k2 >> 1, p = k2 & 1; hr = srcy + m * Fin; wc = w1b + (p * Fin) * Fout + g; useY = 1; }
        } else {
            if (k < 12288) { int m = k / 3, j = k - 3 * m; hr = srcy + m * Fin; wc = w2a + (j * Fin) * Fout + g; useY = 1; }
            else { int k2 = k - 12288; int n = k2 >> 1, p = k2 & 1; hr = srcx + n * Fin; wc = w2b + (p * Fin) * Fout + g; useY = 0; }
        }
        float a = 0.f;
        if (use_bn) {
            const float* sc = useY ? stats + 196 : stats + 132;
            const float* sh = useY ? stats + 228 : stats + 164;
            #pragma unroll
            for (int f = 0; f < 32; ++f) {
                float h = sc[f] * hr[f] + sh[f];
                a += h * wc[f * Fout];
            }
        } else {
            for (int f = 0; f < Fin; ++f) a += hr[f] * wc[f * Fout];
        }
        v = a;
    }
    // fragment offset for element (k, g)
    int e = k & 7, kw = (k >> 3) & 3, t = k >> 5, hh = g >> 4;
    int off = (((t * 2 + hh) * 64 + (kw << 4) + (g & 15)) << 3) | e;
    if (!isB2) B1f[off] = f16b(v); else B2f[off] = f16b(v);
}

// ---------------- split-K MFMA GEMM over packed A, 4-wave k-split per tile ----------------
// x-branch: 64 mwgs x 14 ksegs = 896 WGs (segs 0..5 = W, 6..13 = P)
// y-branch: 128 mwgs x 16 ksegs = 2048 WGs (segs 0..11 = WL, 12..15 = PT)
__global__ __launch_bounds__(256) void gemm_k(
    const unsigned short* __restrict__ Wb, const unsigned short* __restrict__ Pb,
    const unsigned short* __restrict__ WLb, const unsigned short* __restrict__ PTb,
    const unsigned short* __restrict__ B1f, const unsigned short* __restrict__ B2f,
    float* __restrict__ px, float* __restrict__ py, float* __restrict__ stats, int nwgx) {
    __shared__ float lds[4][1024];
    int bid = blockIdx.x;
    if (bid == 0 && threadIdx.x < 132) stats[threadIdx.x] = 0.f;  // zero sums + counter for next reduce
    const unsigned short* Bf;
    float* Z;
    int seg, Mbase, K, kloc, kb;
    const unsigned short* A16;
    if (bid < nwgx) {
        Bf = B1f;
        int mwg = bid / 14; seg = bid % 14;
        Mbase = mwg * 32;
        kb = seg << 10;
        Z = px + (size_t)seg * 65536;
        if (seg < 6) { K = 6144; kloc = kb;        A16 = Wb; }
        else         { K = 8192; kloc = kb - 6144; A16 = Pb; }
    } else {
        int b2 = bid - nwgx;
        Bf = B2f;
        int mwg = b2 / 16; seg = b2 % 16;
        Mbase = mwg * 32;
        kb = seg << 10;
        Z = py + (size_t)seg * 131072;
        if (seg < 12) { K = 12288; kloc = kb;         A16 = WLb; }
        else          { K = 4096;  kloc = kb - 12288; A16 = PTb; }
    }
    int wid = threadIdx.x >> 6, lane = threadIdx.x & 63;
    int kq = wid << 8;  // this wave's 256-K quarter
    const unsigned short* ap0 = A16 + (size_t)(Mbase >> 4) * (K * 16)
                              + (size_t)((kloc + kq) >> 5) * 512 + lane * 8;
    const unsigned short* ap1 = ap0 + (size_t)K * 16;  // next 16-row panel
    const unsigned short* bp = Bf + ((size_t)((kb + kq) >> 5)) * 1024 + lane * 8;
    f32x4 acc00 = {0.f,0.f,0.f,0.f}, acc01 = {0.f,0.f,0.f,0.f};
    f32x4 acc10 = {0.f,0.f,0.f,0.f}, acc11 = {0.f,0.f,0.f,0.f};
    #pragma unroll
    for (int ks = 0; ks < 8; ++ks) {
        f16x8 a0 = *(const f16x8*)ap0;
        f16x8 a1 = *(const f16x8*)ap1;
        f16x8 b0 = *(const f16x8*)bp;
        f16x8 b1 = *(const f16x8*)(bp + 512);
        acc00 = __builtin_amdgcn_mfma_f32_16x16x32_f16(a0, b0, acc00, 0, 0, 0);
        acc10 = __builtin_amdgcn_mfma_f32_16x16x32_f16(a1, b0, acc10, 0, 0, 0);
        acc01 = __builtin_amdgcn_mfma_f32_16x16x32_f16(a0, b1, acc01, 0, 0, 0);
        acc11 = __builtin_amdgcn_mfma_f32_16x16x32_f16(a1, b1, acc11, 0, 0, 0);
        ap0 += 512; ap1 += 512; bp += 1024;
    }
    int col = lane & 15, r0 = (lane >> 4) << 2;
    float* l = lds[wid];
    #pragma unroll
    for (int r = 0; r < 4; ++r) {
        l[(r0 + r) * 32 + col]            = acc00[r];
        l[(r0 + r) * 32 + col + 16]       = acc01[r];
        l[(r0 + r + 16) * 32 + col]       = acc10[r];
        l[(r0 + r + 16) * 32 + col + 16]  = acc11[r];
    }
    __syncthreads();
    int t = threadIdx.x;
    float4 a = ((const float4*)lds[0])[t];
    float4 b = ((const float4*)lds[1])[t];
    float4 c = ((const float4*)lds[2])[t];
    float4 d = ((const float4*)lds[3])[t];
    float4 s;
    s.x = (a.x + b.x) + (c.x + d.x);
    s.y = (a.y + b.y) + (c.y + d.y);
    s.z = (a.z + b.z) + (c.z + d.z);
    s.w = (a.w + b.w) + (c.w + d.w);
    ((float4*)(Z + (size_t)Mbase * 32))[t] = s;
}

// ---------------- reduce partials + bias + relu-half + column stats + BN finalize ----------------
__global__ __launch_bounds__(256) void reduce_stats(
    const float* __restrict__ px, const float* __restrict__ py,
    const float* __restrict__ bx, const float* __restrict__ by,
    const float* __restrict__ gx, const float* __restrict__ btx,
    const float* __restrict__ gy, const float* __restrict__ bty,
    float* __restrict__ zax, float* __restrict__ zay,
    float* __restrict__ stats) {
    __shared__ float lsum[4][8][8];
    __shared__ int lastFlag;
    int bid = blockIdx.x, tid = threadIdx.x;
    const float4* src; const float* bias; float4* dst; float* st; int nseg, i4, stride4;
    if (bid < 64) { src = (const float4*)px; bias = bx; dst = (float4*)zax; st = stats;      nseg = 14; i4 = bid * 256 + tid;        stride4 = 16384; }
    else          { src = (const float4*)py; bias = by; dst = (float4*)zay; st = stats + 64; nseg = 16; i4 = (bid - 64) * 256 + tid; stride4 = 32768; }
    float4 s = {0.f, 0.f, 0.f, 0.f};
    for (int g = 0; g < nseg; ++g) {
        float4 v = src[(size_t)g * stride4 + i4];
        s.x += v.x; s.y += v.y; s.z += v.z; s.w += v.w;
    }
    int c0 = (i4 & 7) * 4;
    float4 b4 = *(const float4*)(bias + c0);
    s.x += b4.x; s.y += b4.y; s.z += b4.z; s.w += b4.w;
    if (c0 < 16) {
        s.x = fmaxf(s.x, 0.f); s.y = fmaxf(s.y, 0.f);
        s.z = fmaxf(s.z, 0.f); s.w = fmaxf(s.w, 0.f);
    }
    dst[i4] = s;
    float4 s2 = {s.x * s.x, s.y * s.y, s.z * s.z, s.w * s.w};
    #pragma unroll
    for (int mask = 8; mask <= 32; mask <<= 1) {
        s.x += __shfl_xor(s.x, mask); s.y += __shfl_xor(s.y, mask);
        s.z += __shfl_xor(s.z, mask); s.w += __shfl_xor(s.w, mask);
        s2.x += __shfl_xor(s2.x, mask); s2.y += __shfl_xor(s2.y, mask);
        s2.z += __shfl_xor(s2.z, mask); s2.w += __shfl_xor(s2.w, mask);
    }
    int w = tid >> 6, ln = tid & 63;
    if (ln < 8) {
        lsum[w][ln][0] = s.x;  lsum[w][ln][1] = s.y;  lsum[w][ln][2] = s.z;  lsum[w][ln][3] = s.w;
        lsum[w][ln][4] = s2.x; lsum[w][ln][5] = s2.y; lsum[w][ln][6] = s2.z; lsum[w][ln][7] = s2.w;
    }
    __syncthreads();
    if (tid < 64) {
        int q = tid >> 3, e = tid & 7;
        float v = lsum[0][q][e] + lsum[1][q][e] + lsum[2][q][e] + lsum[3][q][e];
        int col = q * 4 + (e & 3);
        atomAddF((e < 4) ? &st[col] : &st[32 + col], v);
    }
    __syncthreads();
    if (tid == 0) {
        __threadfence();
        int old = __hip_atomic_fetch_add((int*)(stats + 128), 1, __ATOMIC_ACQ_REL, __HIP_MEMORY_SCOPE_AGENT);
        lastFlag = (old == 191) ? 1 : 0;
    }
    __syncthreads();
    if (lastFlag && tid < 64) {
        int f = tid & 31, isY = tid >> 5;
        float* sb = stats + (isY ? 64 : 0);
        float n = isY ? 4096.f : 2048.f;
        float sum = __hip_atomic_load(&sb[f], __ATOMIC_RELAXED, __HIP_MEMORY_SCOPE_AGENT);
        float ssq = __hip_atomic_load(&sb[32 + f], __ATOMIC_RELAXED, __HIP_MEMORY_SCOPE_AGENT);
        float mean = sum / n;
        float var = ssq / n - mean * mean;
        const float* gv = isY ? gy : gx;
        const float* bv = isY ? bty : btx;
        float sc = gv[f] * rsqrtf(var + 1e-5f);
        stats[132 + isY * 64 + f] = sc;
        stats[164 + isY * 64 + f] = bv[f] - mean * sc;
    }
}

// ---------------- final: sum x-partials + bl -> out ----------------
__global__ __launch_bounds__(256) void out_final(const float* __restrict__ px,
                                                 const float* __restrict__ bl,
                                                 float* __restrict__ out) {
    int tid = blockIdx.x * 256 + threadIdx.x;
    if (tid < 4096) {
        int n = tid >> 1, c = tid & 1;
        float a = bl[c];
        for (int s = 0; s < 14; ++s) a += px[(size_t)s * 65536 + n * 32 + c];
        out[tid] = a;
    }
}

extern "C" void kernel_launch(void* const* d_in, const int* in_sizes, int n_in,
                              void* d_out, int out_size, void* d_ws, size_t ws_size,
                              hipStream_t stream) {
    const float* W    = (const float*)d_in[0];
    const float* x    = (const float*)d_in[1];
    const float* WL   = (const float*)d_in[2];
    const float* y    = (const float*)d_in[3];
    const float* P    = (const float*)d_in[4];
    const float* wx2x0 = (const float*)d_in[5];
    const float* wy2x0 = (const float*)d_in[6];
    const float* bx0   = (const float*)d_in[7];
    const float* wy2y0 = (const float*)d_in[8];
    const float* wx2y0 = (const float*)d_in[9];
    const float* by0   = (const float*)d_in[10];
    const float* gx0   = (const float*)d_in[11];
    const float* btx0  = (const float*)d_in[12];
    const float* gy0   = (const float*)d_in[13];
    const float* bty0  = (const float*)d_in[14];
    const float* wx2x_m = (const float*)d_in[15];
    const float* wy2x_m = (const float*)d_in[16];
    const float* bx_m   = (const float*)d_in[17];
    const float* wy2y_m = (const float*)d_in[18];
    const float* wx2y_m = (const float*)d_in[19];
    const float* by_m   = (const float*)d_in[20];
    const float* gx_m   = (const float*)d_in[21];
    const float* btx_m  = (const float*)d_in[22];
    const float* gy_m   = (const float*)d_in[23];
    const float* bty_m  = (const float*)d_in[24];
    const float* wlx = (const float*)d_in[25];
    const float* wly = (const float*)d_in[26];
    const float* bl  = (const float*)d_in[27];

    char* base = (char*)d_ws;
    unsigned short* Wb  = (unsigned short*)(base + 0);          // 25,165,824 B
    unsigned short* Pb  = (unsigned short*)(base + 25165824);   // 33,554,432 B
    unsigned short* WLb = (unsigned short*)(base + 58720256);   // 100,663,296 B
    unsigned short* PTb = (unsigned short*)(base + 159383552);  // 33,554,432 B
    unsigned short* B1f = (unsigned short*)(base + 192937984);  // 917,504 B
    unsigned short* B2f = (unsigned short*)(base + 193855488);  // 1,048,576 B
    float* zax   = (float*)(base + 194904064);  // 262,144 B
    float* zay   = (float*)(base + 195166208);  // 524,288 B
    float* stats = (float*)(base + 195690496);  // 2,048 B
    float* px    = (float*)(base + 195692544);  // 3,670,016 B
    float* py    = (float*)(base + 199362560);  // 8,388,608 B

    // one-time conversions (merged): cvt W/WL + transpose/pack P
    prep<<<6144, 256, 0, stream>>>(W, WL, P, Wb, WLb, Pb, PTb);

    // block 0 (Fin = 1, raw x/y, no bn)
    build_b<<<3840, 256, 0, stream>>>(x, y, 1, 32, 1, 0, stats,
                                      wx2x0, wy2x0, wy2y0, wx2y0, B1f, B2f);
    gemm_k<<<2944, 256, 0, stream>>>(Wb, Pb, WLb, PTb, B1f, B2f, px, py, stats, 896);
    reduce_stats<<<192, 256, 0, stream>>>(px, py, bx0, by0, gx0, btx0, gy0, bty0, zax, zay, stats);

    // blocks 1..6 (middle weights i = 0..5); reduce_i finalizes BN of block i
    for (int i = 0; i < 6; ++i) {
        build_b<<<3840, 256, 0, stream>>>(zax, zay, 32, 32, 1, 1, stats,
                                          wx2x_m + i * 3072, wy2x_m + i * 2048,
                                          wy2y_m + i * 3072, wx2y_m + i * 2048, B1f, B2f);
        gemm_k<<<2944, 256, 0, stream>>>(Wb, Pb, WLb, PTb, B1f, B2f, px, py, stats, 896);
        reduce_stats<<<192, 256, 0, stream>>>(px, py, bx_m + i * 32, by_m + i * 32,
                                              gx_m + i * 32, btx_m + i * 32,
                                              gy_m + i * 32, bty_m + i * 32, zax, zay, stats);
    }

    // final layer: consumes BN of block 6, linear weights, x-branch only
    build_b<<<1792, 256, 0, stream>>>(zax, zay, 32, 2, 0, 1, stats,
                                      wlx, wly, nullptr, nullptr, B1f, B2f);
    gemm_k<<<896, 256, 0, stream>>>(Wb, Pb, WLb, PTb, B1f, B2f, px, py, stats, 896);
    out_final<<<16, 256, 0, stream>>>(px, bl, (float*)d_out);
}

// Round 16
// 602.726 us; speedup vs baseline: 7.4372x; 1.0259x over previous
//
#include <hip/hip_runtime.h>

typedef _Float16 f16x8 __attribute__((ext_vector_type(8)));
typedef float f32x4 __attribute__((ext_vector_type(4)));

// Packed ("fragment-major") A layout: half-index of element (row,k), row-length K:
//   off = (row>>4)*(K*16) + (k>>5)*512 + ((((k>>3)&3)*16 + (row&15))*8) + (k&7)
// A wave reading lane*8..lane*8+7 at one kstep gets a contiguous 1KB block ==
// its MFMA A-fragment (row = lane&15, k = kstep*32 + (lane>>4)*8 + e).
//
// stats layout (floats): [0..63] x sums (sum,sumsq), [64..127] y sums, [128] counter,
//                        [132..163] scx, [164..195] shx, [196..227] scy, [228..259] shy

__device__ inline unsigned short f16b(float v) {
    _Float16 h = (_Float16)v;
    return __builtin_bit_cast(unsigned short, h);
}

__device__ inline void atomAddF(float* p, float v) {
    __hip_atomic_fetch_add(p, v, __ATOMIC_RELAXED, __HIP_MEMORY_SCOPE_AGENT);
}

// ---------------- fp32 -> packed fp16, 4 units (one 128B src row-chunk) per call ----------------
template<int K>
__device__ inline void pack_cvt4(const float* __restrict__ src, unsigned short* __restrict__ dst, int q) {
    const int KSTEPS = K / 32;
    int r15 = q & 15;
    int blk = q >> 4;
    int panel = blk / KSTEPS;
    int kstep = blk - panel * KSTEPS;
    int row = (panel << 4) | r15;
    const float4* s = (const float4*)(src + (size_t)row * K + (kstep << 5));
    uint4* d = (uint4*)dst;
    #pragma unroll
    for (int g = 0; g < 4; ++g) {
        float4 v0 = s[g * 2], v1 = s[g * 2 + 1];
        uint4 qq;
        qq.x = (unsigned)f16b(v0.x) | ((unsigned)f16b(v0.y) << 16);
        qq.y = (unsigned)f16b(v0.z) | ((unsigned)f16b(v0.w) << 16);
        qq.z = (unsigned)f16b(v1.x) | ((unsigned)f16b(v1.y) << 16);
        qq.w = (unsigned)f16b(v1.z) | ((unsigned)f16b(v1.w) << 16);
        d[(size_t)blk * 64 + g * 16 + r15] = qq;
    }
}

// ---------------- B-matrix element build (fragment layout), shared by prep & build_b ----------------
__device__ inline void build_one(int t2,
    const float* __restrict__ srcx, const float* __restrict__ srcy,
    int Fin, int Fout, int buildB2, int use_bn,
    const float* __restrict__ stats,
    const float* __restrict__ w1a, const float* __restrict__ w1b,
    const float* __restrict__ w2a, const float* __restrict__ w2b,
    unsigned short* __restrict__ B1f, unsigned short* __restrict__ B2f) {
    const int NB1 = 14336 * 32;
    int isB2 = 0;
    if (t2 >= NB1) {
        if (!buildB2) return;
        isB2 = 1; t2 -= NB1;
        if (t2 >= 16384 * 32) return;
    }
    int g = t2 & 31;
    int k = t2 >> 5;
    float v = 0.f;
    if (g < Fout) {
        const float* hr; const float* wc; int useY;
        if (!isB2) {
            if (k < 6144) { int m = k / 3, j = k - 3 * m; hr = srcx + m * Fin; wc = w1a + (j * Fin) * Fout + g; useY = 0; }
            else { int k2 = k - 6144; int m = k2 >> 1, p = k2 & 1; hr = srcy + m * Fin; wc = w1b + (p * Fin) * Fout + g; useY = 1; }
        } else {
            if (k < 12288) { int m = k / 3, j = k - 3 * m; hr = srcy + m * Fin; wc = w2a + (j * Fin) * Fout + g; useY = 1; }
            else { int k2 = k - 12288; int n = k2 >> 1, p = k2 & 1; hr = srcx + n * Fin; wc = w2b + (p * Fin) * Fout + g; useY = 0; }
        }
        float a = 0.f;
        if (use_bn) {
            const float* sc = useY ? stats + 196 : stats + 132;
            const float* sh = useY ? stats + 228 : stats + 164;
            #pragma unroll
            for (int f = 0; f < 32; ++f) {
                float h = sc[f] * hr[f] + sh[f];
                a += h * wc[f * Fout];
            }
        } else {
            for (int f = 0; f < Fin; ++f) a += hr[f] * wc[f * Fout];
        }
        v = a;
    }
    int e = k & 7, kw = (k >> 3) & 3, t = k >> 5, hh = g >> 4;
    int off = (((t * 2 + hh) * 64 + (kw << 4) + (g & 15)) << 3) | e;
    if (!isB2) B1f[off] = f16b(v); else B2f[off] = f16b(v);
}

// ---------------- prep: [0,2048) cvt W/WL; [2048,6144) transpose P (coalesced writes);
//                  [6144,9984) build B of layer 0 ----------------
__global__ __launch_bounds__(256) void prep(const float* __restrict__ W, const float* __restrict__ WL,
                                            const float* __restrict__ P,
                                            const float* __restrict__ x, const float* __restrict__ y,
                                            const float* __restrict__ wx2x0, const float* __restrict__ wy2x0,
                                            const float* __restrict__ wy2y0, const float* __restrict__ wx2y0,
                                            unsigned short* __restrict__ Wb, unsigned short* __restrict__ WLb,
                                            unsigned short* __restrict__ Pb, unsigned short* __restrict__ PT,
                                            unsigned short* __restrict__ B1f, unsigned short* __restrict__ B2f) {
    __shared__ unsigned int lds[64][33];
    int bid = blockIdx.x;
    int tid = threadIdx.x;
    if (bid < 2048) {
        const int QW = 393216, QTOT = 393216 + 1572864;
        for (int q = bid * 256 + tid; q < QTOT; q += 2048 * 256) {
            if (q < QW) pack_cvt4<6144>(W, Wb, q);
            else pack_cvt4<12288>(WL, WLb, q - QW);
        }
        return;
    }
    if (bid >= 6144) {
        build_one((bid - 6144) * 256 + tid, x, y, 1, 32, 1, 0, nullptr,
                  wx2x0, wy2x0, wy2y0, wx2y0, B1f, B2f);
        return;
    }
    int vb = bid - 2048;
    int m0 = (vb & 127) * 32;
    int n0 = (vb >> 7) * 64;
    const float2* P2 = (const float2*)P;
    #pragma unroll
    for (int it = 0; it < 8; ++it) {
        int idx = it * 256 + tid;
        int nl = idx >> 5, ml = idx & 31;
        float2 v = P2[(size_t)(n0 + nl) * 4096 + (m0 + ml)];
        unsigned int pk = (unsigned int)f16b(v.x) | ((unsigned int)f16b(v.y) << 16);
        lds[nl][ml] = pk;
    }
    __syncthreads();
    // coalesced 16B-unit writes: each unit = 8 consecutive halves of the packed layout
    uint4* PT4 = (uint4*)PT;
    uint4* Pb4 = (uint4*)Pb;
    #pragma unroll
    for (int it = 0; it < 2; ++it) {
        int t2 = it * 256 + tid;
        // PT unit: row = m (2 panels), k = n*2+p (4 ksteps)
        {
            int r15 = t2 & 15, kw = (t2 >> 4) & 3, ksi = (t2 >> 6) & 3, pi = t2 >> 8;
            int ml = pi * 16 + r15;
            int nl0 = ksi * 16 + kw * 4;
            uint4 u;
            u.x = lds[nl0][ml]; u.y = lds[nl0 + 1][ml]; u.z = lds[nl0 + 2][ml]; u.w = lds[nl0 + 3][ml];
            int rowp = (m0 >> 4) + pi;
            int ks = (n0 >> 4) + ksi;
            PT4[(size_t)rowp * 8192 + ks * 64 + kw * 16 + r15] = u;   // K=4096: 65536 halves/panel
        }
        // Pb unit: row = n (4 panels), k = m*2+p (2 ksteps)
        {
            int r15 = t2 & 15, kw = (t2 >> 4) & 3, ksi = (t2 >> 6) & 1, pi = t2 >> 7;
            int nl = pi * 16 + r15;
            int ml0 = ksi * 16 + kw * 4;
            uint4 u;
            u.x = lds[nl][ml0]; u.y = lds[nl][ml0 + 1]; u.z = lds[nl][ml0 + 2]; u.w = lds[nl][ml0 + 3];
            int rowp = (n0 >> 4) + pi;
            int ks = (m0 >> 4) + ksi;
            Pb4[(size_t)rowp * 16384 + ks * 64 + kw * 16 + r15] = u;  // K=8192: 131072 halves/panel
        }
    }
}

// ---------------- B-matrix build kernel (middle/final layers) ----------------
__global__ __launch_bounds__(256) void build_b(
    const float* __restrict__ srcx, const float* __restrict__ srcy,
    int Fin, int Fout, int buildB2, int use_bn,
    const float* __restrict__ stats,
    const float* __restrict__ w1a, const float* __restrict__ w1b,
    const float* __restrict__ w2a, const float* __restrict__ w2b,
    unsigned short* __restrict__ B1f, unsigned short* __restrict__ B2f) {
    build_one(blockIdx.x * 256 + threadIdx.x, srcx, srcy, Fin, Fout, buildB2, use_bn,
              stats, w1a, w1b, w2a, w2b, B1f, B2f);
}

// ---------------- split-K MFMA GEMM over packed A, 4-wave k-split per tile ----------------
// x-branch: 64 mwgs x 14 ksegs = 896 WGs (segs 0..5 = W, 6..13 = P)
// y-branch: 128 mwgs x 16 ksegs = 2048 WGs (segs 0..11 = WL, 12..15 = PT)
__global__ __launch_bounds__(256) void gemm_k(
    const unsigned short* __restrict__ Wb, const unsigned short* __restrict__ Pb,
    const unsigned short* __restrict__ WLb, const unsigned short* __restrict__ PTb,
    const unsigned short* __restrict__ B1f, const unsigned short* __restrict__ B2f,
    float* __restrict__ px, float* __restrict__ py, float* __restrict__ stats, int nwgx) {
    __shared__ float lds[4][1024];
    int bid = blockIdx.x;
    if (bid == 0 && threadIdx.x < 132) stats[threadIdx.x] = 0.f;  // zero sums + counter for next reduce
    const unsigned short* Bf;
    float* Z;
    int seg, Mbase, K, kloc, kb;
    const unsigned short* A16;
    if (bid < nwgx) {
        Bf = B1f;
        int mwg = bid / 14; seg = bid % 14;
        Mbase = mwg * 32;
        kb = seg << 10;
        Z = px + (size_t)seg * 65536;
        if (seg < 6) { K = 6144; kloc = kb;        A16 = Wb; }
        else         { K = 8192; kloc = kb - 6144; A16 = Pb; }
    } else {
        int b2 = bid - nwgx;
        Bf = B2f;
        int mwg = b2 / 16; seg = b2 % 16;
        Mbase = mwg * 32;
        kb = seg << 10;
        Z = py + (size_t)seg * 131072;
        if (seg < 12) { K = 12288; kloc = kb;         A16 = WLb; }
        else          { K = 4096;  kloc = kb - 12288; A16 = PTb; }
    }
    int wid = threadIdx.x >> 6, lane = threadIdx.x & 63;
    int kq = wid << 8;  // this wave's 256-K quarter
    const unsigned short* ap0 = A16 + (size_t)(Mbase >> 4) * (K * 16)
                              + (size_t)((kloc + kq) >> 5) * 512 + lane * 8;
    const unsigned short* ap1 = ap0 + (size_t)K * 16;  // next 16-row panel
    const unsigned short* bp = Bf + ((size_t)((kb + kq) >> 5)) * 1024 + lane * 8;
    f32x4 acc00 = {0.f,0.f,0.f,0.f}, acc01 = {0.f,0.f,0.f,0.f};
    f32x4 acc10 = {0.f,0.f,0.f,0.f}, acc11 = {0.f,0.f,0.f,0.f};
    #pragma unroll
    for (int ks = 0; ks < 8; ++ks) {
        f16x8 a0 = *(const f16x8*)ap0;
        f16x8 a1 = *(const f16x8*)ap1;
        f16x8 b0 = *(const f16x8*)bp;
        f16x8 b1 = *(const f16x8*)(bp + 512);
        acc00 = __builtin_amdgcn_mfma_f32_16x16x32_f16(a0, b0, acc00, 0, 0, 0);
        acc10 = __builtin_amdgcn_mfma_f32_16x16x32_f16(a1, b0, acc10, 0, 0, 0);
        acc01 = __builtin_amdgcn_mfma_f32_16x16x32_f16(a0, b1, acc01, 0, 0, 0);
        acc11 = __builtin_amdgcn_mfma_f32_16x16x32_f16(a1, b1, acc11, 0, 0, 0);
        ap0 += 512; ap1 += 512; bp += 1024;
    }
    int col = lane & 15, r0 = (lane >> 4) << 2;
    float* l = lds[wid];
    #pragma unroll
    for (int r = 0; r < 4; ++r) {
        l[(r0 + r) * 32 + col]            = acc00[r];
        l[(r0 + r) * 32 + col + 16]       = acc01[r];
        l[(r0 + r + 16) * 32 + col]       = acc10[r];
        l[(r0 + r + 16) * 32 + col + 16]  = acc11[r];
    }
    __syncthreads();
    int t = threadIdx.x;
    float4 a = ((const float4*)lds[0])[t];
    float4 b = ((const float4*)lds[1])[t];
    float4 c = ((const float4*)lds[2])[t];
    float4 d = ((const float4*)lds[3])[t];
    float4 s;
    s.x = (a.x + b.x) + (c.x + d.x);
    s.y = (a.y + b.y) + (c.y + d.y);
    s.z = (a.z + b.z) + (c.z + d.z);
    s.w = (a.w + b.w) + (c.w + d.w);
    ((float4*)(Z + (size_t)Mbase * 32))[t] = s;
}

// ---------------- reduce partials + bias + relu-half + column stats + BN finalize ----------------
__global__ __launch_bounds__(256) void reduce_stats(
    const float* __restrict__ px, const float* __restrict__ py,
    const float* __restrict__ bx, const float* __restrict__ by,
    const float* __restrict__ gx, const float* __restrict__ btx,
    const float* __restrict__ gy, const float* __restrict__ bty,
    float* __restrict__ zax, float* __restrict__ zay,
    float* __restrict__ stats) {
    __shared__ float lsum[4][8][8];
    __shared__ int lastFlag;
    int bid = blockIdx.x, tid = threadIdx.x;
    const float4* src; const float* bias; float4* dst; float* st; int nseg, i4, stride4;
    if (bid < 64) { src = (const float4*)px; bias = bx; dst = (float4*)zax; st = stats;      nseg = 14; i4 = bid * 256 + tid;        stride4 = 16384; }
    else          { src = (const float4*)py; bias = by; dst = (float4*)zay; st = stats + 64; nseg = 16; i4 = (bid - 64) * 256 + tid; stride4 = 32768; }
    float4 s = {0.f, 0.f, 0.f, 0.f};
    for (int g = 0; g < nseg; ++g) {
        float4 v = src[(size_t)g * stride4 + i4];
        s.x += v.x; s.y += v.y; s.z += v.z; s.w += v.w;
    }
    int c0 = (i4 & 7) * 4;
    float4 b4 = *(const float4*)(bias + c0);
    s.x += b4.x; s.y += b4.y; s.z += b4.z; s.w += b4.w;
    if (c0 < 16) {
        s.x = fmaxf(s.x, 0.f); s.y = fmaxf(s.y, 0.f);
        s.z = fmaxf(s.z, 0.f); s.w = fmaxf(s.w, 0.f);
    }
    dst[i4] = s;
    float4 s2 = {s.x * s.x, s.y * s.y, s.z * s.z, s.w * s.w};
    #pragma unroll
    for (int mask = 8; mask <= 32; mask <<= 1) {
        s.x += __shfl_xor(s.x, mask); s.y += __shfl_xor(s.y, mask);
        s.z += __shfl_xor(s.z, mask); s.w += __shfl_xor(s.w, mask);
        s2.x += __shfl_xor(s2.x, mask); s2.y += __shfl_xor(s2.y, mask);
        s2.z += __shfl_xor(s2.z, mask); s2.w += __shfl_xor(s2.w, mask);
    }
    int w = tid >> 6, ln = tid & 63;
    if (ln < 8) {
        lsum[w][ln][0] = s.x;  lsum[w][ln][1] = s.y;  lsum[w][ln][2] = s.z;  lsum[w][ln][3] = s.w;
        lsum[w][ln][4] = s2.x; lsum[w][ln][5] = s2.y; lsum[w][ln][6] = s2.z; lsum[w][ln][7] = s2.w;
    }
    __syncthreads();
    if (tid < 64) {
        int q = tid >> 3, e = tid & 7;
        float v = lsum[0][q][e] + lsum[1][q][e] + lsum[2][q][e] + lsum[3][q][e];
        int col = q * 4 + (e & 3);
        atomAddF((e < 4) ? &st[col] : &st[32 + col], v);
    }
    __syncthreads();
    if (tid == 0) {
        __threadfence();
        int old = __hip_atomic_fetch_add((int*)(stats + 128), 1, __ATOMIC_ACQ_REL, __HIP_MEMORY_SCOPE_AGENT);
        lastFlag = (old == 191) ? 1 : 0;
    }
    __syncthreads();
    if (lastFlag && tid < 64) {
        int f = tid & 31, isY = tid >> 5;
        float* sb = stats + (isY ? 64 : 0);
        float n = isY ? 4096.f : 2048.f;
        float sum = __hip_atomic_load(&sb[f], __ATOMIC_RELAXED, __HIP_MEMORY_SCOPE_AGENT);
        float ssq = __hip_atomic_load(&sb[32 + f], __ATOMIC_RELAXED, __HIP_MEMORY_SCOPE_AGENT);
        float mean = sum / n;
        float var = ssq / n - mean * mean;
        const float* gv = isY ? gy : gx;
        const float* bv = isY ? bty : btx;
        float sc = gv[f] * rsqrtf(var + 1e-5f);
        stats[132 + isY * 64 + f] = sc;
        stats[164 + isY * 64 + f] = bv[f] - mean * sc;
    }
}

// ---------------- final: sum x-partials + bl -> out ----------------
__global__ __launch_bounds__(256) void out_final(const float* __restrict__ px,
                                                 const float* __restrict__ bl,
                                                 float* __restrict__ out) {
    int tid = blockIdx.x * 256 + threadIdx.x;
    if (tid < 4096) {
        int n = tid >> 1, c = tid & 1;
        float a = bl[c];
        for (int s = 0; s < 14; ++s) a += px[(size_t)s * 65536 + n * 32 + c];
        out[tid] = a;
    }
}

extern "C" void kernel_launch(void* const* d_in, const int* in_sizes, int n_in,
                              void* d_out, int out_size, void* d_ws, size_t ws_size,
                              hipStream_t stream) {
    const float* W    = (const float*)d_in[0];
    const float* x    = (const float*)d_in[1];
    const float* WL   = (const float*)d_in[2];
    const float* y    = (const float*)d_in[3];
    const float* P    = (const float*)d_in[4];
    const float* wx2x0 = (const float*)d_in[5];
    const float* wy2x0 = (const float*)d_in[6];
    const float* bx0   = (const float*)d_in[7];
    const float* wy2y0 = (const float*)d_in[8];
    const float* wx2y0 = (const float*)d_in[9];
    const float* by0   = (const float*)d_in[10];
    const float* gx0   = (const float*)d_in[11];
    const float* btx0  = (const float*)d_in[12];
    const float* gy0   = (const float*)d_in[13];
    const float* bty0  = (const float*)d_in[14];
    const float* wx2x_m = (const float*)d_in[15];
    const float* wy2x_m = (const float*)d_in[16];
    const float* bx_m   = (const float*)d_in[17];
    const float* wy2y_m = (const float*)d_in[18];
    const float* wx2y_m = (const float*)d_in[19];
    const float* by_m   = (const float*)d_in[20];
    const float* gx_m   = (const float*)d_in[21];
    const float* btx_m  = (const float*)d_in[22];
    const float* gy_m   = (const float*)d_in[23];
    const float* bty_m  = (const float*)d_in[24];
    const float* wlx = (const float*)d_in[25];
    const float* wly = (const float*)d_in[26];
    const float* bl  = (const float*)d_in[27];

    char* base = (char*)d_ws;
    unsigned short* Wb  = (unsigned short*)(base + 0);          // 25,165,824 B
    unsigned short* Pb  = (unsigned short*)(base + 25165824);   // 33,554,432 B
    unsigned short* WLb = (unsigned short*)(base + 58720256);   // 100,663,296 B
    unsigned short* PTb = (unsigned short*)(base + 159383552);  // 33,554,432 B
    unsigned short* B1f = (unsigned short*)(base + 192937984);  // 917,504 B
    unsigned short* B2f = (unsigned short*)(base + 193855488);  // 1,048,576 B
    float* zax   = (float*)(base + 194904064);  // 262,144 B
    float* zay   = (float*)(base + 195166208);  // 524,288 B
    float* stats = (float*)(base + 195690496);  // 2,048 B
    float* px    = (float*)(base + 195692544);  // 3,670,016 B
    float* py    = (float*)(base + 199362560);  // 8,388,608 B

    // one-time conversions + layer-0 B build, all in one launch
    prep<<<9984, 256, 0, stream>>>(W, WL, P, x, y, wx2x0, wy2x0, wy2y0, wx2y0,
                                   Wb, WLb, Pb, PTb, B1f, B2f);

    gemm_k<<<2944, 256, 0, stream>>>(Wb, Pb, WLb, PTb, B1f, B2f, px, py, stats, 896);
    reduce_stats<<<192, 256, 0, stream>>>(px, py, bx0, by0, gx0, btx0, gy0, bty0, zax, zay, stats);

    // blocks 1..6 (middle weights i = 0..5); reduce_i finalizes BN of block i
    for (int i = 0; i < 6; ++i) {
        build_b<<<3840, 256, 0, stream>>>(zax, zay, 32, 32, 1, 1, stats,
                                          wx2x_m + i * 3072, wy2x_m + i * 2048,
                                          wy2y_m + i * 3072, wx2y_m + i * 2048, B1f, B2f);
        gemm_k<<<2944, 256, 0, stream>>>(Wb, Pb, WLb, PTb, B1f, B2f, px, py, stats, 896);
        reduce_stats<<<192, 256, 0, stream>>>(px, py, bx_m + i * 32, by_m + i * 32,
                                              gx_m + i * 32, btx_m + i * 32,
                                              gy_m + i * 32, bty_m + i * 32, zax, zay, stats);
    }

    // final layer: consumes BN of block 6, linear weights, x-branch only
    build_b<<<1792, 256, 0, stream>>>(zax, zay, 32, 2, 0, 1, stats,
                                      wlx, wly, nullptr, nullptr, B1f, B2f);
    gemm_k<<<896, 256, 0, stream>>>(Wb, Pb, WLb, PTb, B1f, B2f, px, py, stats, 896);
    out_final<<<16, 256, 0, stream>>>(px, bl, (float*)d_out);
}

// Round 17
// 589.429 us; speedup vs baseline: 7.6049x; 1.0226x over previous
//
#include <hip/hip_runtime.h>

typedef _Float16 f16x8 __attribute__((ext_vector_type(8)));
typedef float f32x4 __attribute__((ext_vector_type(4)));
typedef unsigned short us4v __attribute__((ext_vector_type(4)));

// Packed ("fragment-major") A layout: half-index of element (row,k), row-length K:
//   off = (row>>4)*(K*16) + (k>>5)*512 + ((((k>>3)&3)*16 + (row&15))*8) + (k&7)
// 16B unit index: panel*(K*2) + kstep*64 + g*16 + r15
//
// stats layout (floats): [0..63] x sums (sum,sumsq), [64..127] y sums, [128] counter,
//                        [132..163] scx, [164..195] shx, [196..227] scy, [228..259] shy

#define LPITCH 1036  // halves; 2072B row pitch: 8B-aligned, ~2-way-free banks

__device__ inline unsigned short f16b(float v) {
    _Float16 h = (_Float16)v;
    return __builtin_bit_cast(unsigned short, h);
}

__device__ inline void atomAddF(float* p, float v) {
    __hip_atomic_fetch_add(p, v, __ATOMIC_RELAXED, __HIP_MEMORY_SCOPE_AGENT);
}

// ---------------- LDS-staged cvt: one 16-row x 32-kstep tile per block ----------------
// reads: per wave 1KB contiguous (quarter-row); writes: per wave 1KB contiguous units
template<int K>
__device__ inline void cvt_tile(const float* __restrict__ src, unsigned short* __restrict__ dst,
                                int panel, int t0, unsigned short* lbuf) {
    int tid = threadIdx.x;
    int w = tid >> 6, lane = tid & 63;
    const float* base = src + (size_t)(panel * 16) * K + t0 * 1024;
    #pragma unroll 4
    for (int i = 0; i < 16; ++i) {
        float4 v = *((const float4*)(base + (size_t)i * K + w * 256) + lane);
        us4v h;
        h[0] = f16b(v.x); h[1] = f16b(v.y); h[2] = f16b(v.z); h[3] = f16b(v.w);
        *(us4v*)(lbuf + i * LPITCH + w * 256 + lane * 4) = h;
    }
    __syncthreads();
    uint4* d = (uint4*)dst + (size_t)panel * (K * 2) + t0 * 2048;
    #pragma unroll
    for (int j = 0; j < 8; ++j) {
        int u = j * 256 + tid;
        int r15 = u & 15, g = (u >> 4) & 3, ksl = u >> 6;
        const unsigned short* p = lbuf + r15 * LPITCH + ksl * 32 + g * 8;
        uint2 lo = *(const uint2*)p;
        uint2 hi = *(const uint2*)(p + 4);
        uint4 q; q.x = lo.x; q.y = lo.y; q.z = hi.x; q.w = hi.y;
        d[u] = q;
    }
}

// ---------------- B-matrix element build (fragment layout) ----------------
__device__ inline void build_one(int t2,
    const float* __restrict__ srcx, const float* __restrict__ srcy,
    int Fin, int Fout, int buildB2, int use_bn,
    const float* __restrict__ stats,
    const float* __restrict__ w1a, const float* __restrict__ w1b,
    const float* __restrict__ w2a, const float* __restrict__ w2b,
    unsigned short* __restrict__ B1f, unsigned short* __restrict__ B2f) {
    const int NB1 = 14336 * 32;
    int isB2 = 0;
    if (t2 >= NB1) {
        if (!buildB2) return;
        isB2 = 1; t2 -= NB1;
        if (t2 >= 16384 * 32) return;
    }
    int g = t2 & 31;
    int k = t2 >> 5;
    float v = 0.f;
    if (g < Fout) {
        const float* hr; const float* wc; int useY;
        if (!isB2) {
            if (k < 6144) { int m = k / 3, j = k - 3 * m; hr = srcx + m * Fin; wc = w1a + (j * Fin) * Fout + g; useY = 0; }
            else { int k2 = k - 6144; int m = k2 >> 1, p = k2 & 1; hr = srcy + m * Fin; wc = w1b + (p * Fin) * Fout + g; useY = 1; }
        } else {
            if (k < 12288) { int m = k / 3, j = k - 3 * m; hr = srcy + m * Fin; wc = w2a + (j * Fin) * Fout + g; useY = 1; }
            else { int k2 = k - 12288; int n = k2 >> 1, p = k2 & 1; hr = srcx + n * Fin; wc = w2b + (p * Fin) * Fout + g; useY = 0; }
        }
        float a = 0.f;
        if (use_bn) {
            const float* sc = useY ? stats + 196 : stats + 132;
            const float* sh = useY ? stats + 228 : stats + 164;
            #pragma unroll
            for (int f = 0; f < 32; ++f) {
                float h = sc[f] * hr[f] + sh[f];
                a += h * wc[f * Fout];
            }
        } else {
            for (int f = 0; f < Fin; ++f) a += hr[f] * wc[f * Fout];
        }
        v = a;
    }
    int e = k & 7, kw = (k >> 3) & 3, t = k >> 5, hh = g >> 4;
    int off = (((t * 2 + hh) * 64 + (kw << 4) + (g & 15)) << 3) | e;
    if (!isB2) B1f[off] = f16b(v); else B2f[off] = f16b(v);
}

// ---------------- prep: [0,3840) cvt tiles; [3840,7936) transpose P; [7936,11776) build0 ----------------
__global__ __launch_bounds__(256) void prep(const float* __restrict__ W, const float* __restrict__ WL,
                                            const float* __restrict__ P,
                                            const float* __restrict__ x, const float* __restrict__ y,
                                            const float* __restrict__ wx2x0, const float* __restrict__ wy2x0,
                                            const float* __restrict__ wy2y0, const float* __restrict__ wx2y0,
                                            unsigned short* __restrict__ Wb, unsigned short* __restrict__ WLb,
                                            unsigned short* __restrict__ Pb, unsigned short* __restrict__ PT,
                                            unsigned short* __restrict__ B1f, unsigned short* __restrict__ B2f) {
    __shared__ __align__(16) unsigned char smem[16 * LPITCH * 2];
    int bid = blockIdx.x;
    int tid = threadIdx.x;
    if (bid < 3840) {
        unsigned short* lbuf = (unsigned short*)smem;
        if (bid < 768) cvt_tile<6144>(W, Wb, bid / 6, bid % 6, lbuf);
        else { int b = bid - 768; cvt_tile<12288>(WL, WLb, b / 12, b % 12, lbuf); }
        return;
    }
    if (bid >= 7936) {
        build_one((bid - 7936) * 256 + tid, x, y, 1, 32, 1, 0, nullptr,
                  wx2x0, wy2x0, wy2y0, wx2y0, B1f, B2f);
        return;
    }
    unsigned int (*lds)[33] = (unsigned int (*)[33])smem;
    int vb = bid - 3840;
    int m0 = (vb & 127) * 32;
    int n0 = (vb >> 7) * 64;
    const float2* P2 = (const float2*)P;
    #pragma unroll
    for (int it = 0; it < 8; ++it) {
        int idx = it * 256 + tid;
        int nl = idx >> 5, ml = idx & 31;
        float2 v = P2[(size_t)(n0 + nl) * 4096 + (m0 + ml)];
        unsigned int pk = (unsigned int)f16b(v.x) | ((unsigned int)f16b(v.y) << 16);
        lds[nl][ml] = pk;
    }
    __syncthreads();
    uint4* PT4 = (uint4*)PT;
    uint4* Pb4 = (uint4*)Pb;
    #pragma unroll
    for (int it = 0; it < 2; ++it) {
        int t2 = it * 256 + tid;
        {   // PT unit: row = m (2 panels), k = n*2+p (4 ksteps)
            int r15 = t2 & 15, kw = (t2 >> 4) & 3, ksi = (t2 >> 6) & 3, pi = t2 >> 8;
            int ml = pi * 16 + r15;
            int nl0 = ksi * 16 + kw * 4;
            uint4 u;
            u.x = lds[nl0][ml]; u.y = lds[nl0 + 1][ml]; u.z = lds[nl0 + 2][ml]; u.w = lds[nl0 + 3][ml];
            int rowp = (m0 >> 4) + pi;
            int ks = (n0 >> 4) + ksi;
            PT4[(size_t)rowp * 8192 + ks * 64 + kw * 16 + r15] = u;
        }
        {   // Pb unit: row = n (4 panels), k = m*2+p (2 ksteps)
            int r15 = t2 & 15, kw = (t2 >> 4) & 3, ksi = (t2 >> 6) & 1, pi = t2 >> 7;
            int nl = pi * 16 + r15;
            int ml0 = ksi * 16 + kw * 4;
            uint4 u;
            u.x = lds[nl][ml0]; u.y = lds[nl][ml0 + 1]; u.z = lds[nl][ml0 + 2]; u.w = lds[nl][ml0 + 3];
            int rowp = (n0 >> 4) + pi;
            int ks = (m0 >> 4) + ksi;
            Pb4[(size_t)rowp * 16384 + ks * 64 + kw * 16 + r15] = u;
        }
    }
}

// ---------------- B-matrix build kernel (middle/final layers) ----------------
__global__ __launch_bounds__(256) void build_b(
    const float* __restrict__ srcx, const float* __restrict__ srcy,
    int Fin, int Fout, int buildB2, int use_bn,
    const float* __restrict__ stats,
    const float* __restrict__ w1a, const float* __restrict__ w1b,
    const float* __restrict__ w2a, const float* __restrict__ w2b,
    unsigned short* __restrict__ B1f, unsigned short* __restrict__ B2f) {
    build_one(blockIdx.x * 256 + threadIdx.x, srcx, srcy, Fin, Fout, buildB2, use_bn,
              stats, w1a, w1b, w2a, w2b, B1f, B2f);
}

// ---------------- split-K MFMA GEMM over packed A, 4-wave k-split, 1-deep prefetch ----------------
__global__ __launch_bounds__(256) void gemm_k(
    const unsigned short* __restrict__ Wb, const unsigned short* __restrict__ Pb,
    const unsigned short* __restrict__ WLb, const unsigned short* __restrict__ PTb,
    const unsigned short* __restrict__ B1f, const unsigned short* __restrict__ B2f,
    float* __restrict__ px, float* __restrict__ py, float* __restrict__ stats, int nwgx) {
    __shared__ float lds[4][1024];
    int bid = blockIdx.x;
    if (bid == 0 && threadIdx.x < 132) stats[threadIdx.x] = 0.f;
    const unsigned short* Bf;
    float* Z;
    int seg, Mbase, K, kloc, kb;
    const unsigned short* A16;
    if (bid < nwgx) {
        Bf = B1f;
        int mwg = bid / 14; seg = bid % 14;
        Mbase = mwg * 32;
        kb = seg << 10;
        Z = px + (size_t)seg * 65536;
        if (seg < 6) { K = 6144; kloc = kb;        A16 = Wb; }
        else         { K = 8192; kloc = kb - 6144; A16 = Pb; }
    } else {
        int b2 = bid - nwgx;
        Bf = B2f;
        int mwg = b2 / 16; seg = b2 % 16;
        Mbase = mwg * 32;
        kb = seg << 10;
        Z = py + (size_t)seg * 131072;
        if (seg < 12) { K = 12288; kloc = kb;         A16 = WLb; }
        else          { K = 4096;  kloc = kb - 12288; A16 = PTb; }
    }
    int wid = threadIdx.x >> 6, lane = threadIdx.x & 63;
    int kq = wid << 8;
    const unsigned short* ap0 = A16 + (size_t)(Mbase >> 4) * (K * 16)
                              + (size_t)((kloc + kq) >> 5) * 512 + lane * 8;
    const unsigned short* ap1 = ap0 + (size_t)K * 16;
    const unsigned short* bp = Bf + ((size_t)((kb + kq) >> 5)) * 1024 + lane * 8;
    f32x4 acc00 = {0.f,0.f,0.f,0.f}, acc01 = {0.f,0.f,0.f,0.f};
    f32x4 acc10 = {0.f,0.f,0.f,0.f}, acc11 = {0.f,0.f,0.f,0.f};
    f16x8 a0 = *(const f16x8*)ap0;
    f16x8 a1 = *(const f16x8*)ap1;
    f16x8 b0 = *(const f16x8*)bp;
    f16x8 b1 = *(const f16x8*)(bp + 512);
    #pragma unroll
    for (int ks = 0; ks < 7; ++ks) {
        ap0 += 512; ap1 += 512; bp += 1024;
        f16x8 na0 = *(const f16x8*)ap0;
        f16x8 na1 = *(const f16x8*)ap1;
        f16x8 nb0 = *(const f16x8*)bp;
        f16x8 nb1 = *(const f16x8*)(bp + 512);
        acc00 = __builtin_amdgcn_mfma_f32_16x16x32_f16(a0, b0, acc00, 0, 0, 0);
        acc10 = __builtin_amdgcn_mfma_f32_16x16x32_f16(a1, b0, acc10, 0, 0, 0);
        acc01 = __builtin_amdgcn_mfma_f32_16x16x32_f16(a0, b1, acc01, 0, 0, 0);
        acc11 = __builtin_amdgcn_mfma_f32_16x16x32_f16(a1, b1, acc11, 0, 0, 0);
        a0 = na0; a1 = na1; b0 = nb0; b1 = nb1;
    }
    acc00 = __builtin_amdgcn_mfma_f32_16x16x32_f16(a0, b0, acc00, 0, 0, 0);
    acc10 = __builtin_amdgcn_mfma_f32_16x16x32_f16(a1, b0, acc10, 0, 0, 0);
    acc01 = __builtin_amdgcn_mfma_f32_16x16x32_f16(a0, b1, acc01, 0, 0, 0);
    acc11 = __builtin_amdgcn_mfma_f32_16x16x32_f16(a1, b1, acc11, 0, 0, 0);
    int col = lane & 15, r0 = (lane >> 4) << 2;
    float* l = lds[wid];
    #pragma unroll
    for (int r = 0; r < 4; ++r) {
        l[(r0 + r) * 32 + col]            = acc00[r];
        l[(r0 + r) * 32 + col + 16]       = acc01[r];
        l[(r0 + r + 16) * 32 + col]       = acc10[r];
        l[(r0 + r + 16) * 32 + col + 16]  = acc11[r];
    }
    __syncthreads();
    int t = threadIdx.x;
    float4 a = ((const float4*)lds[0])[t];
    float4 b = ((const float4*)lds[1])[t];
    float4 c = ((const float4*)lds[2])[t];
    float4 d = ((const float4*)lds[3])[t];
    float4 s;
    s.x = (a.x + b.x) + (c.x + d.x);
    s.y = (a.y + b.y) + (c.y + d.y);
    s.z = (a.z + b.z) + (c.z + d.z);
    s.w = (a.w + b.w) + (c.w + d.w);
    ((float4*)(Z + (size_t)Mbase * 32))[t] = s;
}

// ---------------- reduce partials + bias + relu-half + column stats + BN finalize ----------------
__global__ __launch_bounds__(256) void reduce_stats(
    const float* __restrict__ px, const float* __restrict__ py,
    const float* __restrict__ bx, const float* __restrict__ by,
    const float* __restrict__ gx, const float* __restrict__ btx,
    const float* __restrict__ gy, const float* __restrict__ bty,
    float* __restrict__ zax, float* __restrict__ zay,
    float* __restrict__ stats) {
    __shared__ float lsum[4][8][8];
    __shared__ int lastFlag;
    int bid = blockIdx.x, tid = threadIdx.x;
    const float4* src; const float* bias; float4* dst; float* st; int nseg, i4, stride4;
    if (bid < 64) { src = (const float4*)px; bias = bx; dst = (float4*)zax; st = stats;      nseg = 14; i4 = bid * 256 + tid;        stride4 = 16384; }
    else          { src = (const float4*)py; bias = by; dst = (float4*)zay; st = stats + 64; nseg = 16; i4 = (bid - 64) * 256 + tid; stride4 = 32768; }
    float4 s = {0.f, 0.f, 0.f, 0.f};
    for (int g = 0; g < nseg; ++g) {
        float4 v = src[(size_t)g * stride4 + i4];
        s.x += v.x; s.y += v.y; s.z += v.z; s.w += v.w;
    }
    int c0 = (i4 & 7) * 4;
    float4 b4 = *(const float4*)(bias + c0);
    s.x += b4.x; s.y += b4.y; s.z += b4.z; s.w += b4.w;
    if (c0 < 16) {
        s.x = fmaxf(s.x, 0.f); s.y = fmaxf(s.y, 0.f);
        s.z = fmaxf(s.z, 0.f); s.w = fmaxf(s.w, 0.f);
    }
    dst[i4] = s;
    float4 s2 = {s.x * s.x, s.y * s.y, s.z * s.z, s.w * s.w};
    #pragma unroll
    for (int mask = 8; mask <= 32; mask <<= 1) {
        s.x += __shfl_xor(s.x, mask); s.y += __shfl_xor(s.y, mask);
        s.z += __shfl_xor(s.z, mask); s.w += __shfl_xor(s.w, mask);
        s2.x += __shfl_xor(s2.x, mask); s2.y += __shfl_xor(s2.y, mask);
        s2.z += __shfl_xor(s2.z, mask); s2.w += __shfl_xor(s2.w, mask);
    }
    int w = tid >> 6, ln = tid & 63;
    if (ln < 8) {
        lsum[w][ln][0] = s.x;  lsum[w][ln][1] = s.y;  lsum[w][ln][2] = s.z;  lsum[w][ln][3] = s.w;
        lsum[w][ln][4] = s2.x; lsum[w][ln][5] = s2.y; lsum[w][ln][6] = s2.z; lsum[w][ln][7] = s2.w;
    }
    __syncthreads();
    if (tid < 64) {
        int q = tid >> 3, e = tid & 7;
        float v = lsum[0][q][e] + lsum[1][q][e] + lsum[2][q][e] + lsum[3][q][e];
        int col = q * 4 + (e & 3);
        atomAddF((e < 4) ? &st[col] : &st[32 + col], v);
    }
    __syncthreads();
    if (tid == 0) {
        __threadfence();
        int old = __hip_atomic_fetch_add((int*)(stats + 128), 1, __ATOMIC_ACQ_REL, __HIP_MEMORY_SCOPE_AGENT);
        lastFlag = (old == 191) ? 1 : 0;
    }
    __syncthreads();
    if (lastFlag && tid < 64) {
        int f = tid & 31, isY = tid >> 5;
        float* sb = stats + (isY ? 64 : 0);
        float n = isY ? 4096.f : 2048.f;
        float sum = __hip_atomic_load(&sb[f], __ATOMIC_RELAXED, __HIP_MEMORY_SCOPE_AGENT);
        float ssq = __hip_atomic_load(&sb[32 + f], __ATOMIC_RELAXED, __HIP_MEMORY_SCOPE_AGENT);
        float mean = sum / n;
        float var = ssq / n - mean * mean;
        const float* gv = isY ? gy : gx;
        const float* bv = isY ? bty : btx;
        float sc = gv[f] * rsqrtf(var + 1e-5f);
        stats[132 + isY * 64 + f] = sc;
        stats[164 + isY * 64 + f] = bv[f] - mean * sc;
    }
}

// ---------------- final: sum x-partials + bl -> out ----------------
__global__ __launch_bounds__(256) void out_final(const float* __restrict__ px,
                                                 const float* __restrict__ bl,
                                                 float* __restrict__ out) {
    int tid = blockIdx.x * 256 + threadIdx.x;
    if (tid < 4096) {
        int n = tid >> 1, c = tid & 1;
        float a = bl[c];
        for (int s = 0; s < 14; ++s) a += px[(size_t)s * 65536 + n * 32 + c];
        out[tid] = a;
    }
}

extern "C" void kernel_launch(void* const* d_in, const int* in_sizes, int n_in,
                              void* d_out, int out_size, void* d_ws, size_t ws_size,
                              hipStream_t stream) {
    const float* W    = (const float*)d_in[0];
    const float* x    = (const float*)d_in[1];
    const float* WL   = (const float*)d_in[2];
    const float* y    = (const float*)d_in[3];
    const float* P    = (const float*)d_in[4];
    const float* wx2x0 = (const float*)d_in[5];
    const float* wy2x0 = (const float*)d_in[6];
    const float* bx0   = (const float*)d_in[7];
    const float* wy2y0 = (const float*)d_in[8];
    const float* wx2y0 = (const float*)d_in[9];
    const float* by0   = (const float*)d_in[10];
    const float* gx0   = (const float*)d_in[11];
    const float* btx0  = (const float*)d_in[12];
    const float* gy0   = (const float*)d_in[13];
    const float* bty0  = (const float*)d_in[14];
    const float* wx2x_m = (const float*)d_in[15];
    const float* wy2x_m = (const float*)d_in[16];
    const float* bx_m   = (const float*)d_in[17];
    const float* wy2y_m = (const float*)d_in[18];
    const float* wx2y_m = (const float*)d_in[19];
    const float* by_m   = (const float*)d_in[20];
    const float* gx_m   = (const float*)d_in[21];
    const float* btx_m  = (const float*)d_in[22];
    const float* gy_m   = (const float*)d_in[23];
    const float* bty_m  = (const float*)d_in[24];
    const float* wlx = (const float*)d_in[25];
    const float* wly = (const float*)d_in[26];
    const float* bl  = (const float*)d_in[27];

    char* base = (char*)d_ws;
    unsigned short* Wb  = (unsigned short*)(base + 0);          // 25,165,824 B
    unsigned short* Pb  = (unsigned short*)(base + 25165824);   // 33,554,432 B
    unsigned short* WLb = (unsigned short*)(base + 58720256);   // 100,663,296 B
    unsigned short* PTb = (unsigned short*)(base + 159383552);  // 33,554,432 B
    unsigned short* B1f = (unsigned short*)(base + 192937984);  // 917,504 B
    unsigned short* B2f = (unsigned short*)(base + 193855488);  // 1,048,576 B
    float* zax   = (float*)(base + 194904064);  // 262,144 B
    float* zay   = (float*)(base + 195166208);  // 524,288 B
    float* stats = (float*)(base + 195690496);  // 2,048 B
    float* px    = (float*)(base + 195692544);  // 3,670,016 B
    float* py    = (float*)(base + 199362560);  // 8,388,608 B

    // one-time conversions + layer-0 B build, all in one launch
    prep<<<11776, 256, 0, stream>>>(W, WL, P, x, y, wx2x0, wy2x0, wy2y0, wx2y0,
                                    Wb, WLb, Pb, PTb, B1f, B2f);

    gemm_k<<<2944, 256, 0, stream>>>(Wb, Pb, WLb, PTb, B1f, B2f, px, py, stats, 896);
    reduce_stats<<<192, 256, 0, stream>>>(px, py, bx0, by0, gx0, btx0, gy0, bty0, zax, zay, stats);

    // blocks 1..6 (middle weights i = 0..5); reduce_i finalizes BN of block i
    for (int i = 0; i < 6; ++i) {
        build_b<<<3840, 256, 0, stream>>>(zax, zay, 32, 32, 1, 1, stats,
                                          wx2x_m + i * 3072, wy2x_m + i * 2048,
                                          wy2y_m + i * 3072, wx2y_m + i * 2048, B1f, B2f);
        gemm_k<<<2944, 256, 0, stream>>>(Wb, Pb, WLb, PTb, B1f, B2f, px, py, stats, 896);
        reduce_stats<<<192, 256, 0, stream>>>(px, py, bx_m + i * 32, by_m + i * 32,
                                              gx_m + i * 32, btx_m + i * 32,
                                              gy_m + i * 32, bty_m + i * 32, zax, zay, stats);
    }

    // final layer: consumes BN of block 6, linear weights, x-branch only
    build_b<<<1792, 256, 0, stream>>>(zax, zay, 32, 2, 0, 1, stats,
                                      wlx, wly, nullptr, nullptr, B1f, B2f);
    gemm_k<<<896, 256, 0, stream>>>(Wb, Pb, WLb, PTb, B1f, B2f, px, py, stats, 896);
    out_final<<<16, 256, 0, stream>>>(px, bl, (float*)d_out);
}